// Round 1
// baseline (10791.761 us; speedup 1.0000x reference)
//
#include <hip/hip_runtime.h>

#define NUM_SYM 50000
#define NUM_HERB 50000
#define N_NODES (NUM_SYM + NUM_HERB)
#define DIM 128

// Edge-parallel SpMM: out[rows[e]] += vals[e] * x[cols[e]], x virtualized as
// two base pointers (xa for node < NUM_SYM, xb for the rest). 32 threads per
// edge, each thread owns one float4 (4 dims) of the 128-dim row.
__global__ __launch_bounds__(256) void spmm_scatter(
    const int* __restrict__ rows, const int* __restrict__ cols,
    const float* __restrict__ vals, int n_edges,
    const float* __restrict__ xa, const float* __restrict__ xb,
    float* __restrict__ out)
{
    int gid = blockIdx.x * 256 + threadIdx.x;
    int edge = gid >> 5;
    if (edge >= n_edges) return;
    int sub = gid & 31;

    int c = cols[edge];
    int r = rows[edge];
    float v = vals[edge];

    const float* xrow = (c < NUM_SYM) ? (xa + (size_t)c * DIM)
                                      : (xb + (size_t)(c - NUM_SYM) * DIM);
    float4 m = reinterpret_cast<const float4*>(xrow)[sub];

    float* o = out + (size_t)r * DIM + (size_t)sub * 4;
    // unsafeAtomicAdd -> hardware global_atomic_add_f32 (no CAS loop).
    unsafeAtomicAdd(o + 0, v * m.x);
    unsafeAtomicAdd(o + 1, v * m.y);
    unsafeAtomicAdd(o + 2, v * m.z);
    unsafeAtomicAdd(o + 3, v * m.w);
}

// out = (ego + e1 + out) / 3, float4-vectorized.
__global__ __launch_bounds__(256) void finalize_mean(
    const float* __restrict__ sym, const float* __restrict__ herb,
    const float* __restrict__ e1, float* __restrict__ out)
{
    int i = blockIdx.x * 256 + threadIdx.x;     // float4 index
    const int n4 = N_NODES * DIM / 4;
    if (i >= n4) return;
    const int sym4 = NUM_SYM * DIM / 4;

    float4 e = (i < sym4) ? reinterpret_cast<const float4*>(sym)[i]
                          : reinterpret_cast<const float4*>(herb)[i - sym4];
    float4 a = reinterpret_cast<const float4*>(e1)[i];
    float4 b = reinterpret_cast<float4*>(out)[i];

    const float s = 1.0f / 3.0f;
    float4 r;
    r.x = (e.x + a.x + b.x) * s;
    r.y = (e.y + a.y + b.y) * s;
    r.z = (e.z + a.z + b.z) * s;
    r.w = (e.w + a.w + b.w) * s;
    reinterpret_cast<float4*>(out)[i] = r;
}

extern "C" void kernel_launch(void* const* d_in, const int* in_sizes, int n_in,
                              void* d_out, int out_size, void* d_ws, size_t ws_size,
                              hipStream_t stream) {
    const float* sym  = (const float*)d_in[0];
    const float* herb = (const float*)d_in[1];
    const int*   rows = (const int*)d_in[2];
    const int*   cols = (const int*)d_in[3];
    const float* vals = (const float*)d_in[4];
    const int E = in_sizes[2];

    float* e1  = (float*)d_ws;                  // [N_NODES, DIM] fp32 = 51.2 MB
    float* out = (float*)d_out;                 // [N_NODES, DIM] fp32

    const size_t nbytes = (size_t)N_NODES * DIM * sizeof(float);
    hipMemsetAsync(e1, 0, nbytes, stream);
    hipMemsetAsync(out, 0, nbytes, stream);

    const int spmm_blocks = (E * 32 + 255) / 256;
    // layer 1: e1 = A @ ego   (ego virtualized from sym/herb)
    spmm_scatter<<<spmm_blocks, 256, 0, stream>>>(rows, cols, vals, E, sym, herb, e1);
    // layer 2: out = A @ e1   (e1 is contiguous [N, D]; split base pointers so
    // the same col<NUM_SYM ? xa : xb indexing lands on e1 + col*DIM)
    spmm_scatter<<<spmm_blocks, 256, 0, stream>>>(rows, cols, vals, E,
                                                  e1, e1 + (size_t)NUM_SYM * DIM, out);
    // out = (ego + e1 + out) / 3
    const int n4 = N_NODES * DIM / 4;
    finalize_mean<<<(n4 + 255) / 256, 256, 0, stream>>>(sym, herb, e1, out);
}

// Round 2
// 967.509 us; speedup vs baseline: 11.1542x; 11.1542x over previous
//
#include <hip/hip_runtime.h>

#define NUM_SYM 50000
#define NUM_HERB 50000
#define N_NODES (NUM_SYM + NUM_HERB)
#define DIM 128
#define SCAN_BS 1024

// ---------------- CSR build ----------------

__global__ __launch_bounds__(256) void hist_rows(
    const int* __restrict__ rows, int E, int* __restrict__ counts)
{
    int e = blockIdx.x * 256 + threadIdx.x;
    if (e < E) atomicAdd(&counts[rows[e]], 1);
}

// Per-block inclusive scan (Hillis-Steele in LDS); writes exclusive values
// and per-block totals.
__global__ __launch_bounds__(SCAN_BS) void scan_a(
    const int* __restrict__ counts, int* __restrict__ excl,
    int* __restrict__ blocksums)
{
    __shared__ int s[SCAN_BS];
    int t = threadIdx.x;
    int i = blockIdx.x * SCAN_BS + t;
    int v = (i < N_NODES) ? counts[i] : 0;
    s[t] = v;
    __syncthreads();
    for (int off = 1; off < SCAN_BS; off <<= 1) {
        int x = (t >= off) ? s[t - off] : 0;
        __syncthreads();
        s[t] += x;
        __syncthreads();
    }
    if (i < N_NODES) excl[i] = s[t] - v;
    if (t == SCAN_BS - 1) blocksums[blockIdx.x] = s[t];
}

// Single-block exclusive scan of the (<=128) block totals.
__global__ __launch_bounds__(128) void scan_b(int* __restrict__ blocksums, int nb)
{
    __shared__ int s[128];
    int t = threadIdx.x;
    int v = (t < nb) ? blocksums[t] : 0;
    s[t] = v;
    __syncthreads();
    for (int off = 1; off < 128; off <<= 1) {
        int x = (t >= off) ? s[t - off] : 0;
        __syncthreads();
        s[t] += x;
        __syncthreads();
    }
    if (t < nb) blocksums[t] = s[t] - v;   // exclusive
}

__global__ __launch_bounds__(SCAN_BS) void scan_c(
    int* __restrict__ cursor, const int* __restrict__ blocksums)
{
    int i = blockIdx.x * SCAN_BS + threadIdx.x;
    if (i < N_NODES) cursor[i] += blocksums[blockIdx.x];
}

// Scatter edges into row-sorted (col,val) pairs. cursor advances to row end.
__global__ __launch_bounds__(256) void scatter_edges(
    const int* __restrict__ rows, const int* __restrict__ cols,
    const float* __restrict__ vals, int E,
    int* __restrict__ cursor, int2* __restrict__ edges)
{
    int e = blockIdx.x * 256 + threadIdx.x;
    if (e >= E) return;
    int r = rows[e];
    int pos = atomicAdd(&cursor[r], 1);
    edges[pos] = make_int2(cols[e], __float_as_int(vals[e]));
}

// ---------------- pull-mode SpMM ----------------
// One wave (64 lanes) per output row; lane owns a float2 (2 of 128 dims).
// After scatter_edges, cursor[row] == row end; start = end - counts[row].
__global__ __launch_bounds__(256) void spmm_pull(
    const int2* __restrict__ edges, const int* __restrict__ cursor,
    const int* __restrict__ counts,
    const float* __restrict__ xa, const float* __restrict__ xb,
    float* __restrict__ out)
{
    int wave = blockIdx.x * 4 + (threadIdx.x >> 6);
    int lane = threadIdx.x & 63;
    if (wave >= N_NODES) return;

    int end = cursor[wave];
    int cnt = counts[wave];
    int j = end - cnt;

    float2 acc = make_float2(0.f, 0.f);
    for (; j + 1 < end; j += 2) {
        int2 e0 = edges[j];
        int2 e1 = edges[j + 1];
        const float* x0 = (e0.x < NUM_SYM) ? xa + (size_t)e0.x * DIM
                                           : xb + (size_t)(e0.x - NUM_SYM) * DIM;
        const float* x1 = (e1.x < NUM_SYM) ? xa + (size_t)e1.x * DIM
                                           : xb + (size_t)(e1.x - NUM_SYM) * DIM;
        float2 m0 = reinterpret_cast<const float2*>(x0)[lane];
        float2 m1 = reinterpret_cast<const float2*>(x1)[lane];
        float v0 = __int_as_float(e0.y);
        float v1 = __int_as_float(e1.y);
        acc.x += v0 * m0.x;
        acc.y += v0 * m0.y;
        acc.x += v1 * m1.x;
        acc.y += v1 * m1.y;
    }
    if (j < end) {
        int2 e0 = edges[j];
        const float* x0 = (e0.x < NUM_SYM) ? xa + (size_t)e0.x * DIM
                                           : xb + (size_t)(e0.x - NUM_SYM) * DIM;
        float2 m0 = reinterpret_cast<const float2*>(x0)[lane];
        float v0 = __int_as_float(e0.y);
        acc.x += v0 * m0.x;
        acc.y += v0 * m0.y;
    }
    reinterpret_cast<float2*>(out + (size_t)wave * DIM)[lane] = acc;
}

// ---------------- epilogue ----------------
__global__ __launch_bounds__(256) void finalize_mean(
    const float* __restrict__ sym, const float* __restrict__ herb,
    const float* __restrict__ e1, float* __restrict__ out)
{
    int i = blockIdx.x * 256 + threadIdx.x;     // float4 index
    const int n4 = N_NODES * DIM / 4;
    if (i >= n4) return;
    const int sym4 = NUM_SYM * DIM / 4;

    float4 e = (i < sym4) ? reinterpret_cast<const float4*>(sym)[i]
                          : reinterpret_cast<const float4*>(herb)[i - sym4];
    float4 a = reinterpret_cast<const float4*>(e1)[i];
    float4 b = reinterpret_cast<float4*>(out)[i];

    const float s = 1.0f / 3.0f;
    float4 r;
    r.x = (e.x + a.x + b.x) * s;
    r.y = (e.y + a.y + b.y) * s;
    r.z = (e.z + a.z + b.z) * s;
    r.w = (e.w + a.w + b.w) * s;
    reinterpret_cast<float4*>(out)[i] = r;
}

// ---------------- fallback (round-1 atomic path) ----------------
__global__ __launch_bounds__(256) void spmm_scatter(
    const int* __restrict__ rows, const int* __restrict__ cols,
    const float* __restrict__ vals, int n_edges,
    const float* __restrict__ xa, const float* __restrict__ xb,
    float* __restrict__ out)
{
    int gid = blockIdx.x * 256 + threadIdx.x;
    int edge = gid >> 5;
    if (edge >= n_edges) return;
    int sub = gid & 31;

    int c = cols[edge];
    int r = rows[edge];
    float v = vals[edge];

    const float* xrow = (c < NUM_SYM) ? (xa + (size_t)c * DIM)
                                      : (xb + (size_t)(c - NUM_SYM) * DIM);
    float4 m = reinterpret_cast<const float4*>(xrow)[sub];
    float* o = out + (size_t)r * DIM + (size_t)sub * 4;
    unsafeAtomicAdd(o + 0, v * m.x);
    unsafeAtomicAdd(o + 1, v * m.y);
    unsafeAtomicAdd(o + 2, v * m.z);
    unsafeAtomicAdd(o + 3, v * m.w);
}

extern "C" void kernel_launch(void* const* d_in, const int* in_sizes, int n_in,
                              void* d_out, int out_size, void* d_ws, size_t ws_size,
                              hipStream_t stream) {
    const float* sym  = (const float*)d_in[0];
    const float* herb = (const float*)d_in[1];
    const int*   rows = (const int*)d_in[2];
    const int*   cols = (const int*)d_in[3];
    const float* vals = (const float*)d_in[4];
    const int E = in_sizes[2];
    float* out = (float*)d_out;

    // workspace layout
    char* ws = (char*)d_ws;
    const size_t e1_bytes     = (size_t)N_NODES * DIM * sizeof(float);  // 51.2 MB
    const size_t counts_off   = e1_bytes;
    const size_t cursor_off   = counts_off + (size_t)N_NODES * 4;
    const size_t bsums_off    = cursor_off + (size_t)N_NODES * 4;
    const size_t edges_off    = bsums_off + 1024;                       // 8B aligned
    const size_t required     = edges_off + (size_t)E * 8;

    float* e1 = (float*)ws;

    if (ws_size < required) {
        // fallback: verified round-1 atomic-scatter path (needs only e1)
        hipMemsetAsync(e1, 0, e1_bytes, stream);
        hipMemsetAsync(out, 0, e1_bytes, stream);
        const int spmm_blocks = (E * 32 + 255) / 256;
        spmm_scatter<<<spmm_blocks, 256, 0, stream>>>(rows, cols, vals, E, sym, herb, e1);
        spmm_scatter<<<spmm_blocks, 256, 0, stream>>>(rows, cols, vals, E,
                                                      e1, e1 + (size_t)NUM_SYM * DIM, out);
        const int n4 = N_NODES * DIM / 4;
        finalize_mean<<<(n4 + 255) / 256, 256, 0, stream>>>(sym, herb, e1, out);
        return;
    }

    int*  counts = (int*)(ws + counts_off);
    int*  cursor = (int*)(ws + cursor_off);
    int*  bsums  = (int*)(ws + bsums_off);
    int2* edges  = (int2*)(ws + edges_off);

    // --- build CSR ---
    hipMemsetAsync(counts, 0, (size_t)N_NODES * 4, stream);
    hist_rows<<<(E + 255) / 256, 256, 0, stream>>>(rows, E, counts);

    const int NB = (N_NODES + SCAN_BS - 1) / SCAN_BS;   // 98
    scan_a<<<NB, SCAN_BS, 0, stream>>>(counts, cursor, bsums);
    scan_b<<<1, 128, 0, stream>>>(bsums, NB);
    scan_c<<<NB, SCAN_BS, 0, stream>>>(cursor, bsums);
    scatter_edges<<<(E + 255) / 256, 256, 0, stream>>>(rows, cols, vals, E, cursor, edges);

    // --- 2 propagation layers (pull mode, no atomics) ---
    const int pull_blocks = (N_NODES + 3) / 4;
    spmm_pull<<<pull_blocks, 256, 0, stream>>>(edges, cursor, counts, sym, herb, e1);
    spmm_pull<<<pull_blocks, 256, 0, stream>>>(edges, cursor, counts,
                                               e1, e1 + (size_t)NUM_SYM * DIM, out);

    // out = (ego + e1 + out) / 3
    const int n4 = N_NODES * DIM / 4;
    finalize_mean<<<(n4 + 255) / 256, 256, 0, stream>>>(sym, herb, e1, out);
}

// Round 3
// 801.180 us; speedup vs baseline: 13.4698x; 1.2076x over previous
//
#include <hip/hip_runtime.h>

#define NUM_SYM 50000
#define NUM_HERB 50000
#define N_NODES (NUM_SYM + NUM_HERB)
#define DIM 128
#define LL_END 0x3FFFFF   // 22-bit sentinel; valid edge indices < 2^22

// ---------------- linked-list build ----------------

__global__ __launch_bounds__(256) void init_head(int* __restrict__ head)
{
    int i = blockIdx.x * 256 + threadIdx.x;
    if (i < N_NODES) head[i] = LL_END;
}

// Node packing (int2):
//   x = (next << 10) | (col >> 7)      next: 22 bits, col high 10 of 17 bits
//   y = (valbits & ~0x7F) | (col & 0x7F)   fp32 val, low 7 mantissa bits = col low
__global__ __launch_bounds__(256) void build_ll(
    const int* __restrict__ rows, const int* __restrict__ cols,
    const float* __restrict__ vals, int E,
    int* __restrict__ head, int2* __restrict__ ll)
{
    int e = blockIdx.x * 256 + threadIdx.x;
    if (e >= E) return;
    int r = rows[e];
    int c = cols[e];
    unsigned vb = (unsigned)__float_as_int(vals[e]);
    int old = atomicExch(&head[r], e);          // device-scope, cross-XCD safe
    int2 nd;
    nd.x = (int)(((unsigned)old << 10) | ((unsigned)c >> 7));
    nd.y = (int)((vb & ~0x7Fu) | ((unsigned)c & 0x7Fu));
    ll[e] = nd;                                  // sequential, coalesced
}

// ---------------- pull-mode SpMM over linked lists ----------------
// 2 rows per wave: lanes 0-31 -> row 2w, lanes 32-63 -> row 2w+1.
// Each lane owns one float4 (4 of 128 dims).
template <bool FUSE_MEAN>
__global__ __launch_bounds__(256) void spmm_ll(
    const int2* __restrict__ ll, const int* __restrict__ head,
    const float* __restrict__ xa, const float* __restrict__ xb,
    const float* __restrict__ sym, const float* __restrict__ herb,
    const float* __restrict__ e1, float* __restrict__ out)
{
    int wave = blockIdx.x * 4 + (threadIdx.x >> 6);
    int half = (threadIdx.x >> 5) & 1;
    int lane = threadIdx.x & 31;
    int r = wave * 2 + half;
    if (r >= N_NODES) return;

    unsigned e = (unsigned)head[r];              // uniform per half-wave
    float4 acc = make_float4(0.f, 0.f, 0.f, 0.f);

    while (e != LL_END) {
        int2 nd = ll[e];                         // 8B uniform load, L2/L3
        unsigned x0 = (unsigned)nd.x;
        unsigned y0 = (unsigned)nd.y;
        unsigned col = ((x0 & 0x3FFu) << 7) | (y0 & 0x7Fu);
        float v = __int_as_float((int)(y0 & ~0x7Fu));
        const float* xrow = (col < NUM_SYM)
            ? xa + (size_t)col * DIM
            : xb + (size_t)(col - NUM_SYM) * DIM;
        float4 m = reinterpret_cast<const float4*>(xrow)[lane];
        acc.x += v * m.x;
        acc.y += v * m.y;
        acc.z += v * m.z;
        acc.w += v * m.w;
        e = x0 >> 10;                            // next
    }

    if (FUSE_MEAN) {
        // out = (ego + e1 + acc) / 3
        const float4* egorow = (r < NUM_SYM)
            ? reinterpret_cast<const float4*>(sym  + (size_t)r * DIM)
            : reinterpret_cast<const float4*>(herb + (size_t)(r - NUM_SYM) * DIM);
        float4 g = egorow[lane];
        float4 a = reinterpret_cast<const float4*>(e1 + (size_t)r * DIM)[lane];
        const float s = 1.0f / 3.0f;
        acc.x = (g.x + a.x + acc.x) * s;
        acc.y = (g.y + a.y + acc.y) * s;
        acc.z = (g.z + a.z + acc.z) * s;
        acc.w = (g.w + a.w + acc.w) * s;
    }
    reinterpret_cast<float4*>(out + (size_t)r * DIM)[lane] = acc;
}

// ---------------- fallback (round-1 verified atomic path) ----------------

__global__ __launch_bounds__(256) void spmm_scatter(
    const int* __restrict__ rows, const int* __restrict__ cols,
    const float* __restrict__ vals, int n_edges,
    const float* __restrict__ xa, const float* __restrict__ xb,
    float* __restrict__ out)
{
    int gid = blockIdx.x * 256 + threadIdx.x;
    int edge = gid >> 5;
    if (edge >= n_edges) return;
    int sub = gid & 31;
    int c = cols[edge];
    int r = rows[edge];
    float v = vals[edge];
    const float* xrow = (c < NUM_SYM) ? (xa + (size_t)c * DIM)
                                      : (xb + (size_t)(c - NUM_SYM) * DIM);
    float4 m = reinterpret_cast<const float4*>(xrow)[sub];
    float* o = out + (size_t)r * DIM + (size_t)sub * 4;
    unsafeAtomicAdd(o + 0, v * m.x);
    unsafeAtomicAdd(o + 1, v * m.y);
    unsafeAtomicAdd(o + 2, v * m.z);
    unsafeAtomicAdd(o + 3, v * m.w);
}

__global__ __launch_bounds__(256) void finalize_mean(
    const float* __restrict__ sym, const float* __restrict__ herb,
    const float* __restrict__ e1, float* __restrict__ out)
{
    int i = blockIdx.x * 256 + threadIdx.x;
    const int n4 = N_NODES * DIM / 4;
    if (i >= n4) return;
    const int sym4 = NUM_SYM * DIM / 4;
    float4 e = (i < sym4) ? reinterpret_cast<const float4*>(sym)[i]
                          : reinterpret_cast<const float4*>(herb)[i - sym4];
    float4 a = reinterpret_cast<const float4*>(e1)[i];
    float4 b = reinterpret_cast<float4*>(out)[i];
    const float s = 1.0f / 3.0f;
    float4 r;
    r.x = (e.x + a.x + b.x) * s;
    r.y = (e.y + a.y + b.y) * s;
    r.z = (e.z + a.z + b.z) * s;
    r.w = (e.w + a.w + b.w) * s;
    reinterpret_cast<float4*>(out)[i] = r;
}

extern "C" void kernel_launch(void* const* d_in, const int* in_sizes, int n_in,
                              void* d_out, int out_size, void* d_ws, size_t ws_size,
                              hipStream_t stream) {
    const float* sym  = (const float*)d_in[0];
    const float* herb = (const float*)d_in[1];
    const int*   rows = (const int*)d_in[2];
    const int*   cols = (const int*)d_in[3];
    const float* vals = (const float*)d_in[4];
    const int E = in_sizes[2];
    float* out = (float*)d_out;

    // workspace layout: e1 [51.2MB] | head [400KB] | ll [E*8 = 25.6MB]
    char* ws = (char*)d_ws;
    const size_t e1_bytes  = (size_t)N_NODES * DIM * sizeof(float);
    const size_t head_off  = e1_bytes;
    const size_t ll_off    = head_off + (size_t)N_NODES * sizeof(int);
    const size_t required  = ll_off + (size_t)E * sizeof(int2);

    float* e1 = (float*)ws;

    if (ws_size < required || E >= (1 << 22)) {
        // fallback: verified round-1 atomic-scatter path
        hipMemsetAsync(e1, 0, e1_bytes, stream);
        hipMemsetAsync(out, 0, e1_bytes, stream);
        const int spmm_blocks = (E * 32 + 255) / 256;
        spmm_scatter<<<spmm_blocks, 256, 0, stream>>>(rows, cols, vals, E, sym, herb, e1);
        spmm_scatter<<<spmm_blocks, 256, 0, stream>>>(rows, cols, vals, E,
                                                      e1, e1 + (size_t)NUM_SYM * DIM, out);
        const int n4 = N_NODES * DIM / 4;
        finalize_mean<<<(n4 + 255) / 256, 256, 0, stream>>>(sym, herb, e1, out);
        return;
    }

    int*  head = (int*)(ws + head_off);
    int2* ll   = (int2*)(ws + ll_off);

    init_head<<<(N_NODES + 255) / 256, 256, 0, stream>>>(head);
    build_ll<<<(E + 255) / 256, 256, 0, stream>>>(rows, cols, vals, E, head, ll);

    // layer 1: e1 = A @ ego   (gather from sym/herb)
    const int blocks = (N_NODES / 2 + 3) / 4;   // 2 rows/wave, 4 waves/block
    spmm_ll<false><<<blocks, 256, 0, stream>>>(ll, head, sym, herb,
                                               nullptr, nullptr, nullptr, e1);
    // layer 2 fused: out = (ego + e1 + A @ e1) / 3
    spmm_ll<true><<<blocks, 256, 0, stream>>>(ll, head,
                                              e1, e1 + (size_t)NUM_SYM * DIM,
                                              sym, herb, e1, out);
}

// Round 4
// 662.668 us; speedup vs baseline: 16.2853x; 1.2090x over previous
//
#include <hip/hip_runtime.h>

#define NUM_SYM 50000
#define NUM_HERB 50000
#define N_NODES (NUM_SYM + NUM_HERB)
#define DIM 128
#define LL_END 0x3FFFFF   // 22-bit sentinel; valid edge indices < 2^22

__device__ __forceinline__ float bf2f(unsigned short u) {
    return __uint_as_float((unsigned)u << 16);
}
__device__ __forceinline__ unsigned short f2bf(float f) {
    unsigned u = __float_as_uint(f);
    unsigned r = (u + 0x7FFFu + ((u >> 16) & 1u)) >> 16;   // round-to-nearest-even
    return (unsigned short)r;
}

// ---------------- bf16 staging of the gather table ----------------
__global__ __launch_bounds__(256) void to_bf16(
    const float* __restrict__ sym, const float* __restrict__ herb,
    ushort* __restrict__ xbf)
{
    int i = blockIdx.x * 256 + threadIdx.x;          // float4 index
    const int n4 = N_NODES * DIM / 4;
    if (i >= n4) return;
    const int sym4 = NUM_SYM * DIM / 4;
    float4 v = (i < sym4) ? reinterpret_cast<const float4*>(sym)[i]
                          : reinterpret_cast<const float4*>(herb)[i - sym4];
    ushort4 o;
    o.x = f2bf(v.x); o.y = f2bf(v.y); o.z = f2bf(v.z); o.w = f2bf(v.w);
    reinterpret_cast<ushort4*>(xbf)[i] = o;
}

// ---------------- linked-list build ----------------
__global__ __launch_bounds__(256) void init_head(int* __restrict__ head)
{
    int i = blockIdx.x * 256 + threadIdx.x;
    if (i < N_NODES) head[i] = LL_END;
}

// Node packing (int2):
//   x = (next << 10) | (col >> 7)          next: 22 bits, col high 10 of 17
//   y = (valbits & ~0x7F) | (col & 0x7F)   fp32 val, low 7 mantissa bits = col low
__global__ __launch_bounds__(256) void build_ll(
    const int* __restrict__ rows, const int* __restrict__ cols,
    const float* __restrict__ vals, int E,
    int* __restrict__ head, int2* __restrict__ ll)
{
    int e = blockIdx.x * 256 + threadIdx.x;
    if (e >= E) return;
    int r = rows[e];
    int c = cols[e];
    unsigned vb = (unsigned)__float_as_int(vals[e]);
    int old = atomicExch(&head[r], e);          // device-scope, cross-XCD safe
    int2 nd;
    nd.x = (int)(((unsigned)old << 10) | ((unsigned)c >> 7));
    nd.y = (int)((vb & ~0x7Fu) | ((unsigned)c & 0x7Fu));
    ll[e] = nd;                                  // sequential, coalesced
}

// ---------------- pull-mode SpMM over linked lists, bf16 gathers ----------
// 2 rows per wave: lanes 0-31 -> row 2w, lanes 32-63 -> row 2w+1.
// Each lane owns 4 of 128 dims (ushort4 gather = 8B/lane, 256B/row).
template <bool FUSE_MEAN>
__global__ __launch_bounds__(256) void spmm_ll_bf16(
    const int2* __restrict__ ll, const int* __restrict__ head,
    const ushort* __restrict__ xbf,              // gather table [N, DIM] bf16
    const float* __restrict__ sym, const float* __restrict__ herb,
    const ushort* __restrict__ e1bf,             // layer-1 result (FUSE only)
    void* __restrict__ outp)
{
    int wave = blockIdx.x * 4 + (threadIdx.x >> 6);
    int half = (threadIdx.x >> 5) & 1;
    int lane = threadIdx.x & 31;
    int r = wave * 2 + half;
    if (r >= N_NODES) return;

    unsigned e = (unsigned)head[r];              // uniform per half-wave
    float4 acc = make_float4(0.f, 0.f, 0.f, 0.f);

    while (e != LL_END) {
        int2 nd = ll[e];                         // 8B uniform load, L2/L3
        unsigned x0 = (unsigned)nd.x;
        unsigned y0 = (unsigned)nd.y;
        unsigned col = ((x0 & 0x3FFu) << 7) | (y0 & 0x7Fu);
        float v = __int_as_float((int)(y0 & ~0x7Fu));
        ushort4 m = reinterpret_cast<const ushort4*>(xbf + (size_t)col * DIM)[lane];
        acc.x += v * bf2f(m.x);
        acc.y += v * bf2f(m.y);
        acc.z += v * bf2f(m.z);
        acc.w += v * bf2f(m.w);
        e = x0 >> 10;                            // next
    }

    if (FUSE_MEAN) {
        // out = (ego + e1 + acc) / 3, fp32 store
        const float4* egorow = (r < NUM_SYM)
            ? reinterpret_cast<const float4*>(sym  + (size_t)r * DIM)
            : reinterpret_cast<const float4*>(herb + (size_t)(r - NUM_SYM) * DIM);
        float4 g = egorow[lane];
        ushort4 a = reinterpret_cast<const ushort4*>(e1bf + (size_t)r * DIM)[lane];
        const float s = 1.0f / 3.0f;
        acc.x = (g.x + bf2f(a.x) + acc.x) * s;
        acc.y = (g.y + bf2f(a.y) + acc.y) * s;
        acc.z = (g.z + bf2f(a.z) + acc.z) * s;
        acc.w = (g.w + bf2f(a.w) + acc.w) * s;
        reinterpret_cast<float4*>((float*)outp + (size_t)r * DIM)[lane] = acc;
    } else {
        ushort4 o;
        o.x = f2bf(acc.x); o.y = f2bf(acc.y); o.z = f2bf(acc.z); o.w = f2bf(acc.w);
        reinterpret_cast<ushort4*>((ushort*)outp + (size_t)r * DIM)[lane] = o;
    }
}

// ---------------- fallback (round-1 verified atomic path) ----------------
__global__ __launch_bounds__(256) void spmm_scatter(
    const int* __restrict__ rows, const int* __restrict__ cols,
    const float* __restrict__ vals, int n_edges,
    const float* __restrict__ xa, const float* __restrict__ xb,
    float* __restrict__ out)
{
    int gid = blockIdx.x * 256 + threadIdx.x;
    int edge = gid >> 5;
    if (edge >= n_edges) return;
    int sub = gid & 31;
    int c = cols[edge];
    int r = rows[edge];
    float v = vals[edge];
    const float* xrow = (c < NUM_SYM) ? (xa + (size_t)c * DIM)
                                      : (xb + (size_t)(c - NUM_SYM) * DIM);
    float4 m = reinterpret_cast<const float4*>(xrow)[sub];
    float* o = out + (size_t)r * DIM + (size_t)sub * 4;
    unsafeAtomicAdd(o + 0, v * m.x);
    unsafeAtomicAdd(o + 1, v * m.y);
    unsafeAtomicAdd(o + 2, v * m.z);
    unsafeAtomicAdd(o + 3, v * m.w);
}

__global__ __launch_bounds__(256) void finalize_mean(
    const float* __restrict__ sym, const float* __restrict__ herb,
    const float* __restrict__ e1, float* __restrict__ out)
{
    int i = blockIdx.x * 256 + threadIdx.x;
    const int n4 = N_NODES * DIM / 4;
    if (i >= n4) return;
    const int sym4 = NUM_SYM * DIM / 4;
    float4 e = (i < sym4) ? reinterpret_cast<const float4*>(sym)[i]
                          : reinterpret_cast<const float4*>(herb)[i - sym4];
    float4 a = reinterpret_cast<const float4*>(e1)[i];
    float4 b = reinterpret_cast<float4*>(out)[i];
    const float s = 1.0f / 3.0f;
    float4 r;
    r.x = (e.x + a.x + b.x) * s;
    r.y = (e.y + a.y + b.y) * s;
    r.z = (e.z + a.z + b.z) * s;
    r.w = (e.w + a.w + b.w) * s;
    reinterpret_cast<float4*>(out)[i] = r;
}

extern "C" void kernel_launch(void* const* d_in, const int* in_sizes, int n_in,
                              void* d_out, int out_size, void* d_ws, size_t ws_size,
                              hipStream_t stream) {
    const float* sym  = (const float*)d_in[0];
    const float* herb = (const float*)d_in[1];
    const int*   rows = (const int*)d_in[2];
    const int*   cols = (const int*)d_in[3];
    const float* vals = (const float*)d_in[4];
    const int E = in_sizes[2];
    float* out = (float*)d_out;

    // workspace layout: xbf [25.6MB] | e1bf [25.6MB] | head [400KB] | ll [25.6MB]
    char* ws = (char*)d_ws;
    const size_t xbf_bytes  = (size_t)N_NODES * DIM * sizeof(ushort);
    const size_t e1bf_off   = xbf_bytes;
    const size_t head_off   = e1bf_off + xbf_bytes;
    const size_t ll_off     = head_off + (size_t)N_NODES * sizeof(int);
    const size_t required   = ll_off + (size_t)E * sizeof(int2);

    if (ws_size < required || E >= (1 << 22)) {
        // fallback: verified round-1 atomic-scatter path (needs only 51.2MB e1)
        float* e1 = (float*)ws;
        const size_t e1_bytes = (size_t)N_NODES * DIM * sizeof(float);
        hipMemsetAsync(e1, 0, e1_bytes, stream);
        hipMemsetAsync(out, 0, e1_bytes, stream);
        const int spmm_blocks = (E * 32 + 255) / 256;
        spmm_scatter<<<spmm_blocks, 256, 0, stream>>>(rows, cols, vals, E, sym, herb, e1);
        spmm_scatter<<<spmm_blocks, 256, 0, stream>>>(rows, cols, vals, E,
                                                      e1, e1 + (size_t)NUM_SYM * DIM, out);
        const int n4 = N_NODES * DIM / 4;
        finalize_mean<<<(n4 + 255) / 256, 256, 0, stream>>>(sym, herb, e1, out);
        return;
    }

    ushort* xbf  = (ushort*)ws;
    ushort* e1bf = (ushort*)(ws + e1bf_off);
    int*    head = (int*)(ws + head_off);
    int2*   ll   = (int2*)(ws + ll_off);

    init_head<<<(N_NODES + 255) / 256, 256, 0, stream>>>(head);
    build_ll<<<(E + 255) / 256, 256, 0, stream>>>(rows, cols, vals, E, head, ll);
    const int n4 = N_NODES * DIM / 4;
    to_bf16<<<(n4 + 255) / 256, 256, 0, stream>>>(sym, herb, xbf);

    // layer 1: e1bf = bf16(A @ ego)
    const int blocks = (N_NODES / 2 + 3) / 4;   // 2 rows/wave, 4 waves/block
    spmm_ll_bf16<false><<<blocks, 256, 0, stream>>>(ll, head, xbf,
                                                    nullptr, nullptr, nullptr, e1bf);
    // layer 2 fused: out = (ego + e1 + A @ e1) / 3
    spmm_ll_bf16<true><<<blocks, 256, 0, stream>>>(ll, head, e1bf,
                                                   sym, herb, e1bf, out);
}